// Round 4
// baseline (293.495 us; speedup 1.0000x reference)
//
#include <hip/hip_runtime.h>

#define EPS 1e-5f
#define SLOPE 0.01f

typedef short short8 __attribute__((ext_vector_type(8)));
typedef float f32x4 __attribute__((ext_vector_type(4)));
typedef float f32x2 __attribute__((ext_vector_type(2)));

static __device__ __forceinline__ unsigned short f32_to_bf16(float x){
  unsigned int u = __float_as_uint(x);
  unsigned int r = u + 0x7FFFu + ((u >> 16) & 1u);
  return (unsigned short)(r >> 16);
}
static __device__ __forceinline__ float bf16lo_to_f32(unsigned int v){
  return __uint_as_float(v << 16);
}
static __device__ __forceinline__ float bf16hi_to_f32(unsigned int v){
  return __uint_as_float(v & 0xFFFF0000u);
}

// 256-thread block exclusive scan helper
static __device__ __forceinline__ int blk_excl_scan(int v){
  __shared__ int wt[4];
  int lane = threadIdx.x & 63, wv = threadIdx.x >> 6;
  int incl = v;
  #pragma unroll
  for (int o = 1; o < 64; o <<= 1){
    int u = __shfl_up(incl, o, 64);
    if (lane >= o) incl += u;
  }
  if (lane == 63) wt[wv] = incl;
  __syncthreads();
  int off = 0;
  #pragma unroll
  for (int i = 0; i < 4; ++i) if (i < wv) off += wt[i];
  return off + incl - v;
}

// ---- packW (192 blocks) + zero cnt64 (blocks 192..) ----------------------
// B frag for tile t (n0=t*16), kstep s (k0=s*32), lane l, elem j:
//   value W[k][n], k = s*32 + (l>>4)*8 + j, n = t*16 + (l&15)

__global__ void k_packzero(const float* __restrict__ W0, const float* __restrict__ W1,
                           const float* __restrict__ W2, short* __restrict__ Bh,
                           short* __restrict__ Bl, unsigned long long* __restrict__ cnt64,
                           int n){
  if ((int)blockIdx.x >= 192){
    int idx = ((int)blockIdx.x - 192)*256 + threadIdx.x;
    if (idx < n) cnt64[idx] = 0ull;
    return;
  }
  int idx = blockIdx.x*256 + threadIdx.x;    // 0..49151
  int which = idx >> 14;
  int r = idx & 16383;
  const float* W = (which == 0) ? W0 : ((which == 1) ? W1 : W2);
  int j = r & 7;
  int l = (r >> 3) & 63;
  int s = (r >> 9) & 3;
  int t = r >> 11;
  int k = s*32 + ((l >> 4) << 3) + j;
  int nn = t*16 + (l & 15);
  float v = W[k*128 + nn];
  unsigned short hb = f32_to_bf16(v);
  float hf = bf16lo_to_f32(hb);
  unsigned short lb = f32_to_bf16(v - hf);
  Bh[idx] = (short)hb;
  Bl[idx] = (short)lb;
}

// ---- fused: edge-count atomics (blocks 0..cntB) + GEMM0 (blocks cntB..) --
// cnt64[d] += (1<<32) | (u32)(w*2^24): hi=count, lo=fixed-point weight sum

__global__ __launch_bounds__(256) void k_fused0(
    const int* __restrict__ dst, const float* __restrict__ ew,
    unsigned long long* __restrict__ cnt64, int* __restrict__ pwr, int E, int cntB,
    const float* __restrict__ X, const short* __restrict__ Bh,
    const short* __restrict__ Bl, unsigned short* __restrict__ Y, int nrows){
  if ((int)blockIdx.x < cntB){
    int e = blockIdx.x*256 + threadIdx.x;
    if (e < E){
      float wv = ew[e];
      unsigned long long add = (1ull << 32) | (unsigned long long)(unsigned int)(wv * 16777216.0f);
      unsigned long long old = atomicAdd(&cnt64[dst[e]], add);
      pwr[e] = (int)(old >> 32);
    }
    return;
  }
  // ---- GEMM0: Y = X(f32) @ W0, split-bf16 A (3 MFMA) ----
  int w    = threadIdx.x >> 6;
  int lane = threadIdx.x & 63;
  int m    = lane & 15;
  int kg   = lane >> 4;
  int row0 = ((int)blockIdx.x - cntB)*64 + w*16;

  f32x4 acc[8];
  #pragma unroll
  for (int t = 0; t < 8; ++t) acc[t] = (f32x4){0.f, 0.f, 0.f, 0.f};

  int arow = row0 + m;
  if (arow >= nrows) arow = nrows - 1;
  const float* ap0 = X + (size_t)arow*128 + (kg << 3);
  const short8* bh0 = (const short8*)Bh + lane;
  const short8* bl0 = (const short8*)Bl + lane;

  #pragma unroll
  for (int s = 0; s < 4; ++s){
    const float* ap = ap0 + s*32;
    float4 a0 = *(const float4*)ap;
    float4 a1 = *(const float4*)(ap + 4);
    float av[8] = {a0.x, a0.y, a0.z, a0.w, a1.x, a1.y, a1.z, a1.w};
    short8 ah, al;
    #pragma unroll
    for (int j = 0; j < 8; ++j){
      unsigned short hb = f32_to_bf16(av[j]);
      float hf = bf16lo_to_f32(hb);
      ah[j] = (short)hb;
      al[j] = (short)f32_to_bf16(av[j] - hf);
    }
    #pragma unroll
    for (int t = 0; t < 8; ++t){
      short8 bh = bh0[t*256 + s*64];
      short8 bl = bl0[t*256 + s*64];
      acc[t] = __builtin_amdgcn_mfma_f32_16x16x32_bf16(ah, bh, acc[t], 0, 0, 0);
      acc[t] = __builtin_amdgcn_mfma_f32_16x16x32_bf16(al, bh, acc[t], 0, 0, 0);
      acc[t] = __builtin_amdgcn_mfma_f32_16x16x32_bf16(ah, bl, acc[t], 0, 0, 0);
    }
  }
  #pragma unroll
  for (int t = 0; t < 8; ++t){
    #pragma unroll
    for (int r = 0; r < 4; ++r){
      int grow = row0 + (kg << 2) + r;
      if (grow < nrows) Y[(size_t)grow*128 + t*16 + m] = f32_to_bf16(acc[t][r]);
    }
  }
}

// ---- scan: block sums, then rowptr + dinv/selfn --------------------------

__global__ void k_scan_a(const unsigned long long* __restrict__ cnt64,
                         int* __restrict__ bsum, int n){
  int idx = blockIdx.x*256 + threadIdx.x;
  int v = (idx < n) ? (int)(cnt64[idx] >> 32) : 0;
  #pragma unroll
  for (int o = 32; o >= 1; o >>= 1) v += __shfl_xor(v, o, 64);
  __shared__ int w4[4];
  if ((threadIdx.x & 63) == 0) w4[threadIdx.x >> 6] = v;
  __syncthreads();
  if (threadIdx.x == 0) bsum[blockIdx.x] = w4[0]+w4[1]+w4[2]+w4[3];
}

__global__ void k_scan_c(const unsigned long long* __restrict__ cnt64,
                         const int* __restrict__ bsum, int* __restrict__ rowptr,
                         float* __restrict__ dinv, float* __restrict__ selfn,
                         int n, int Etot, int nb){
  int tid = threadIdx.x;
  int bid = blockIdx.x;
  int lim = bid < nb ? bid : nb;
  int bv = (tid < lim) ? bsum[tid] : 0;
  #pragma unroll
  for (int o = 32; o >= 1; o >>= 1) bv += __shfl_xor(bv, o, 64);
  __shared__ int w4[4];
  __shared__ int s_boff;
  if ((tid & 63) == 0) w4[tid >> 6] = bv;
  __syncthreads();
  if (tid == 0) s_boff = w4[0]+w4[1]+w4[2]+w4[3];
  __syncthreads();

  int idx = bid*256 + tid;
  unsigned long long c = (idx < n) ? cnt64[idx] : 0ull;
  int v = (int)(c >> 32);
  int ex = blk_excl_scan(v) + s_boff;
  if (idx < n){
    rowptr[idx] = ex;
    float wsum = (float)(unsigned int)(c & 0xFFFFFFFFull) * (1.0f/16777216.0f);
    float dg = 1.0f + wsum;               // + self-loop; always > 0
    dinv[idx]  = rsqrtf(dg);
    selfn[idx] = 1.0f / dg;
  }
  if (idx == 0) rowptr[n] = Etot;
}

// atomic-free fill: packed {src, w}
__global__ void k_fill(const int* __restrict__ src, const int* __restrict__ dst,
                       const float* __restrict__ w, const int* __restrict__ rowptr,
                       const int* __restrict__ pwr, int2* __restrict__ csr, int E){
  int e = blockIdx.x*blockDim.x + threadIdx.x;
  if (e >= E) return;
  int pos = rowptr[dst[e]] + pwr[e];
  csr[pos] = make_int2(src[e], __float_as_int(w[e]));
}

// rewrite w -> dinv[src]*w*dinv[row]
__global__ void k_norm(int2* __restrict__ csr, const int* __restrict__ rowptr,
                       const float* __restrict__ dinv, int n){
  int i = blockIdx.x*blockDim.x + threadIdx.x;
  if (i >= n) return;
  int a = rowptr[i], b = rowptr[i+1];
  float dr = dinv[i];
  for (int e = a; e < b; ++e){
    int2 sn = csr[e];
    float nr = dinv[sn.x] * __int_as_float(sn.y) * dr;
    csr[e].y = __float_as_int(nr);
  }
}

// ---- dense GEMM: Y[n,128](bf16) = Xb[n,128](bf16) @ W (B hi/lo split) ----

__global__ __launch_bounds__(256) void k_gemm_bf16(const unsigned short* __restrict__ Xb,
                                                   const short* __restrict__ Bh,
                                                   const short* __restrict__ Bl,
                                                   unsigned short* __restrict__ Y,
                                                   int nrows){
  int w    = threadIdx.x >> 6;
  int lane = threadIdx.x & 63;
  int m    = lane & 15;
  int kg   = lane >> 4;
  int row0 = blockIdx.x*64 + w*16;

  f32x4 acc[8];
  #pragma unroll
  for (int t = 0; t < 8; ++t) acc[t] = (f32x4){0.f, 0.f, 0.f, 0.f};

  int arow = row0 + m;
  if (arow >= nrows) arow = nrows - 1;
  const short8* ap = (const short8*)(Xb + (size_t)arow*128) + kg;
  const short8* bh0 = (const short8*)Bh + lane;
  const short8* bl0 = (const short8*)Bl + lane;

  #pragma unroll
  for (int s = 0; s < 4; ++s){
    short8 a = ap[s*4];
    #pragma unroll
    for (int t = 0; t < 8; ++t){
      acc[t] = __builtin_amdgcn_mfma_f32_16x16x32_bf16(a, bh0[t*256 + s*64], acc[t], 0, 0, 0);
      acc[t] = __builtin_amdgcn_mfma_f32_16x16x32_bf16(a, bl0[t*256 + s*64], acc[t], 0, 0, 0);
    }
  }
  #pragma unroll
  for (int t = 0; t < 8; ++t){
    #pragma unroll
    for (int r = 0; r < 4; ++r){
      int grow = row0 + (kg << 2) + r;
      if (grow < nrows) Y[(size_t)grow*128 + t*16 + m] = f32_to_bf16(acc[t][r]);
    }
  }
}

// ---- CSR gather + bias (+BN+leaky); Y bf16; out bf16 or f32 --------------
// one wave per node; 16 lanes per edge slot, 4 slots; lane loads 16B (8 ch)

template<bool BN, bool OBF16>
__global__ __launch_bounds__(256) void k_gather(
    const unsigned short* __restrict__ Y, const int* __restrict__ rowptr,
    const int2* __restrict__ csr, const float* __restrict__ selfn,
    const float* __restrict__ bias,
    const float* __restrict__ gam, const float* __restrict__ bet,
    const float* __restrict__ mean, const float* __restrict__ var,
    void* __restrict__ outv, int n){
  int wid  = (blockIdx.x * blockDim.x + threadIdx.x) >> 6;   // node
  int lane = threadIdx.x & 63;
  if (wid >= n) return;
  int g = lane >> 4;          // edge slot 0..3
  int q = lane & 15;          // channel quad (8 channels)

  f32x2 acc[4];
  #pragma unroll
  for (int j = 0; j < 4; ++j) acc[j] = (f32x2){0.f, 0.f};

  int e0 = rowptr[wid], e1 = rowptr[wid+1];
  const char* Yb = (const char*)Y;

  int e = e0 + g;
  for (; e + 4 < e1; e += 8){
    int2 sn0 = csr[e];
    int2 sn1 = csr[e+4];
    float n0 = __int_as_float(sn0.y);
    float n1 = __int_as_float(sn1.y);
    uint4 v0 = *(const uint4*)(Yb + ((size_t)sn0.x << 8) + (q << 4));
    uint4 v1 = *(const uint4*)(Yb + ((size_t)sn1.x << 8) + (q << 4));
    acc[0] += (f32x2){bf16lo_to_f32(v0.x), bf16hi_to_f32(v0.x)} * n0;
    acc[1] += (f32x2){bf16lo_to_f32(v0.y), bf16hi_to_f32(v0.y)} * n0;
    acc[2] += (f32x2){bf16lo_to_f32(v0.z), bf16hi_to_f32(v0.z)} * n0;
    acc[3] += (f32x2){bf16lo_to_f32(v0.w), bf16hi_to_f32(v0.w)} * n0;
    acc[0] += (f32x2){bf16lo_to_f32(v1.x), bf16hi_to_f32(v1.x)} * n1;
    acc[1] += (f32x2){bf16lo_to_f32(v1.y), bf16hi_to_f32(v1.y)} * n1;
    acc[2] += (f32x2){bf16lo_to_f32(v1.z), bf16hi_to_f32(v1.z)} * n1;
    acc[3] += (f32x2){bf16lo_to_f32(v1.w), bf16hi_to_f32(v1.w)} * n1;
  }
  if (e < e1){
    int2 sn0 = csr[e];
    float n0 = __int_as_float(sn0.y);
    uint4 v0 = *(const uint4*)(Yb + ((size_t)sn0.x << 8) + (q << 4));
    acc[0] += (f32x2){bf16lo_to_f32(v0.x), bf16hi_to_f32(v0.x)} * n0;
    acc[1] += (f32x2){bf16lo_to_f32(v0.y), bf16hi_to_f32(v0.y)} * n0;
    acc[2] += (f32x2){bf16lo_to_f32(v0.z), bf16hi_to_f32(v0.z)} * n0;
    acc[3] += (f32x2){bf16lo_to_f32(v0.w), bf16hi_to_f32(v0.w)} * n0;
  }

  float s[8] = {acc[0].x, acc[0].y, acc[1].x, acc[1].y,
                acc[2].x, acc[2].y, acc[3].x, acc[3].y};
  #pragma unroll
  for (int j = 0; j < 8; ++j){
    s[j] += __shfl_xor(s[j], 16, 64);
    s[j] += __shfl_xor(s[j], 32, 64);
  }

  if (g == 0){
    // self term
    uint4 v = *(const uint4*)(Yb + ((size_t)wid << 8) + (q << 4));
    float sf = selfn[wid];
    s[0] += bf16lo_to_f32(v.x)*sf; s[1] += bf16hi_to_f32(v.x)*sf;
    s[2] += bf16lo_to_f32(v.y)*sf; s[3] += bf16hi_to_f32(v.y)*sf;
    s[4] += bf16lo_to_f32(v.z)*sf; s[5] += bf16hi_to_f32(v.z)*sf;
    s[6] += bf16lo_to_f32(v.w)*sf; s[7] += bf16hi_to_f32(v.w)*sf;

    int c = q << 3;
    float4 bi0 = *(const float4*)&bias[c];
    float4 bi1 = *(const float4*)&bias[c+4];
    float o[8] = {s[0]+bi0.x, s[1]+bi0.y, s[2]+bi0.z, s[3]+bi0.w,
                  s[4]+bi1.x, s[5]+bi1.y, s[6]+bi1.z, s[7]+bi1.w};
    if (BN){
      float4 ga0 = *(const float4*)&gam[c],  ga1 = *(const float4*)&gam[c+4];
      float4 bt0 = *(const float4*)&bet[c],  bt1 = *(const float4*)&bet[c+4];
      float4 mn0 = *(const float4*)&mean[c], mn1 = *(const float4*)&mean[c+4];
      float4 vr0 = *(const float4*)&var[c],  vr1 = *(const float4*)&var[c+4];
      float gv[8] = {ga0.x,ga0.y,ga0.z,ga0.w, ga1.x,ga1.y,ga1.z,ga1.w};
      float bv[8] = {bt0.x,bt0.y,bt0.z,bt0.w, bt1.x,bt1.y,bt1.z,bt1.w};
      float mv[8] = {mn0.x,mn0.y,mn0.z,mn0.w, mn1.x,mn1.y,mn1.z,mn1.w};
      float vv[8] = {vr0.x,vr0.y,vr0.z,vr0.w, vr1.x,vr1.y,vr1.z,vr1.w};
      #pragma unroll
      for (int j = 0; j < 8; ++j){
        float a = gv[j] * rsqrtf(vv[j] + EPS);
        float t = (o[j] - mv[j]) * a + bv[j];
        o[j] = t > 0.f ? t : SLOPE*t;
      }
    }
    if (OBF16){
      unsigned int p0 = ((unsigned int)f32_to_bf16(o[1]) << 16) | f32_to_bf16(o[0]);
      unsigned int p1 = ((unsigned int)f32_to_bf16(o[3]) << 16) | f32_to_bf16(o[2]);
      unsigned int p2 = ((unsigned int)f32_to_bf16(o[5]) << 16) | f32_to_bf16(o[4]);
      unsigned int p3 = ((unsigned int)f32_to_bf16(o[7]) << 16) | f32_to_bf16(o[6]);
      *(uint4*)((char*)outv + ((size_t)wid << 8) + (q << 4)) = make_uint4(p0,p1,p2,p3);
    } else {
      float4* op = (float4*)((float*)outv + (size_t)wid*128 + c);
      op[0] = make_float4(o[0], o[1], o[2], o[3]);
      op[1] = make_float4(o[4], o[5], o[6], o[7]);
    }
  }
}

// ---- mean pool over sorted batch (binary search for range) ---------------

__global__ void k_pool(const float* __restrict__ h, const int* __restrict__ batch,
                       float* __restrict__ out, int n){
  __shared__ float red[1024];
  __shared__ int ss[2];
  int g = blockIdx.x;
  if (threadIdx.x < 2){
    int target = g + (int)threadIdx.x;
    int lo = 0, hi = n;
    while (lo < hi){ int mid = (lo + hi) >> 1; if (batch[mid] < target) lo = mid + 1; else hi = mid; }
    ss[threadIdx.x] = lo;
  }
  __syncthreads();
  int a = ss[0], b = ss[1];
  int rg = threadIdx.x >> 7;     // 0..7
  int c  = threadIdx.x & 127;
  float s = 0.f;
  for (int i = a + rg; i < b; i += 8) s += h[(size_t)i*128 + c];
  red[threadIdx.x] = s;
  __syncthreads();
  if (rg == 0){
    float tot = 0.f;
    #pragma unroll
    for (int q = 0; q < 8; ++q) tot += red[c + q*128];
    int cn = b - a;
    out[g*128 + c] = tot / (float)(cn > 0 ? cn : 1);
  }
}

// ---- launch --------------------------------------------------------------

extern "C" void kernel_launch(void* const* d_in, const int* in_sizes, int n_in,
                              void* d_out, int out_size, void* d_ws, size_t ws_size,
                              hipStream_t stream) {
  const int N = in_sizes[0] / 128;
  const int E = in_sizes[1];
  const int G = out_size / 128;
  const int NB = (N + 255) / 256;        // scan blocks
  const int CB = (E + 255) / 256;        // edge blocks
  const int GB = (N + 63) / 64;          // gemm blocks

  const float* x   = (const float*)d_in[0];
  const float* ew  = (const float*)d_in[1];
  const float* W0  = (const float*)d_in[2];
  const float* b0  = (const float*)d_in[3];
  const float* W1  = (const float*)d_in[4];
  const float* b1  = (const float*)d_in[5];
  const float* W2  = (const float*)d_in[6];
  const float* b2  = (const float*)d_in[7];
  const float* g0  = (const float*)d_in[8];
  const float* be0 = (const float*)d_in[9];
  const float* m0  = (const float*)d_in[10];
  const float* v0  = (const float*)d_in[11];
  const float* g1  = (const float*)d_in[12];
  const float* be1 = (const float*)d_in[13];
  const float* m1  = (const float*)d_in[14];
  const float* v1  = (const float*)d_in[15];
  const int*   ei  = (const int*)d_in[16];
  const int*   bat = (const int*)d_in[17];
  float* out = (float*)d_out;

  char* p = (char*)d_ws;
  auto alloc = [&](size_t bytes)->char*{
    char* q = p; p += (bytes + 255) & ~(size_t)255; return q;
  };
  unsigned long long* cnt64 = (unsigned long long*)alloc((size_t)N*8);
  float* dinv   = (float*)alloc((size_t)N*4);
  float* selfn  = (float*)alloc((size_t)N*4);
  int*   rowptr = (int*)  alloc((size_t)(N+1)*4);
  int*   pwr    = (int*)  alloc((size_t)E*4);
  int*   bsum   = (int*)  alloc((size_t)NB*4);
  int2*  csr    = (int2*) alloc((size_t)E*8);
  unsigned short* Y  = (unsigned short*)alloc((size_t)N*128*2);
  unsigned short* Hb = (unsigned short*)alloc((size_t)N*128*2);
  float* H3     = (float*)alloc((size_t)N*128*4);
  short* Bh = (short*)alloc(3*16384*2);
  short* Bl = (short*)alloc(3*16384*2);

  const int* src = ei;
  const int* dst = ei + E;

  k_packzero<<<192 + NB, 256, 0, stream>>>(W0, W1, W2, Bh, Bl, cnt64, N);
  k_fused0  <<<CB + GB, 256, 0, stream>>>(dst, ew, cnt64, pwr, E, CB,
                                          x, Bh, Bl, Y, N);
  k_scan_a  <<<NB, 256, 0, stream>>>(cnt64, bsum, N);
  k_scan_c  <<<NB, 256, 0, stream>>>(cnt64, bsum, rowptr, dinv, selfn, N, E, NB);
  k_fill    <<<CB, 256, 0, stream>>>(src, dst, ew, rowptr, pwr, csr, E);
  k_norm    <<<(N+255)/256, 256, 0, stream>>>(csr, rowptr, dinv, N);

  k_gather<true,true><<<(N+3)/4, 256, 0, stream>>>(Y, rowptr, csr, selfn,
                                                   b0, g0, be0, m0, v0, Hb, N);
  k_gemm_bf16<<<GB, 256, 0, stream>>>(Hb, Bh + 16384, Bl + 16384, Y, N);
  k_gather<true,true><<<(N+3)/4, 256, 0, stream>>>(Y, rowptr, csr, selfn,
                                                   b1, g1, be1, m1, v1, Hb, N);
  k_gemm_bf16<<<GB, 256, 0, stream>>>(Hb, Bh + 32768, Bl + 32768, Y, N);
  k_gather<false,false><<<(N+3)/4, 256, 0, stream>>>(Y, rowptr, csr, selfn,
                                                     b2, nullptr, nullptr, nullptr, nullptr, H3, N);
  k_pool<<<G, 1024, 0, stream>>>(H3, bat, out, N);
}

// Round 5
// 274.314 us; speedup vs baseline: 1.0699x; 1.0699x over previous
//
#include <hip/hip_runtime.h>

#define EPS 1e-5f
#define SLOPE 0.01f

typedef short short8 __attribute__((ext_vector_type(8)));
typedef float f32x4 __attribute__((ext_vector_type(4)));
typedef float f32x2 __attribute__((ext_vector_type(2)));

static __device__ __forceinline__ unsigned short f32_to_bf16(float x){
  unsigned int u = __float_as_uint(x);
  unsigned int r = u + 0x7FFFu + ((u >> 16) & 1u);
  return (unsigned short)(r >> 16);
}
static __device__ __forceinline__ float bf16lo_to_f32(unsigned int v){
  return __uint_as_float(v << 16);
}
static __device__ __forceinline__ float bf16hi_to_f32(unsigned int v){
  return __uint_as_float(v & 0xFFFF0000u);
}

// 256-thread block exclusive scan helper
static __device__ __forceinline__ int blk_excl_scan(int v){
  __shared__ int wt[4];
  int lane = threadIdx.x & 63, wv = threadIdx.x >> 6;
  int incl = v;
  #pragma unroll
  for (int o = 1; o < 64; o <<= 1){
    int u = __shfl_up(incl, o, 64);
    if (lane >= o) incl += u;
  }
  if (lane == 63) wt[wv] = incl;
  __syncthreads();
  int off = 0;
  #pragma unroll
  for (int i = 0; i < 4; ++i) if (i < wv) off += wt[i];
  return off + incl - v;
}

// ---- packW: B frag for tile t, kstep s, lane l, elem j -------------------
//   value W[k][n], k = s*32 + (l>>4)*8 + j, n = t*16 + (l&15)

__global__ void k_packW3(const float* __restrict__ W0, const float* __restrict__ W1,
                         const float* __restrict__ W2, short* __restrict__ Bh,
                         short* __restrict__ Bl){
  int idx = blockIdx.x*256 + threadIdx.x;    // 0..49151
  int which = idx >> 14;
  int r = idx & 16383;
  const float* W = (which == 0) ? W0 : ((which == 1) ? W1 : W2);
  int j = r & 7;
  int l = (r >> 3) & 63;
  int s = (r >> 9) & 3;
  int t = r >> 11;
  int k = s*32 + ((l >> 4) << 3) + j;
  int nn = t*16 + (l & 15);
  float v = W[k*128 + nn];
  unsigned short hb = f32_to_bf16(v);
  float hf = bf16lo_to_f32(hb);
  unsigned short lb = f32_to_bf16(v - hf);
  Bh[idx] = (short)hb;
  Bl[idx] = (short)lb;
}

// ---- fused: packed u32 edge atomics (blocks <cntB) + GEMM0 (rest) --------
// cnt[d] += (1<<24) | u32(w*2^18): hi8=count, lo24=fixed-point weight sum

__global__ __launch_bounds__(256) void k_fused0(
    const int* __restrict__ dst, const float* __restrict__ ew,
    unsigned int* __restrict__ cnt, int* __restrict__ pwr, int E, int cntB,
    const float* __restrict__ X, const short* __restrict__ Bh,
    const short* __restrict__ Bl, unsigned short* __restrict__ Y, int nrows){
  if ((int)blockIdx.x < cntB){
    int e = blockIdx.x*256 + threadIdx.x;
    if (e < E){
      unsigned int add = (1u << 24) | (unsigned int)(ew[e] * 262144.0f);
      unsigned int old = atomicAdd(&cnt[dst[e]], add);
      pwr[e] = (int)(old >> 24);
    }
    return;
  }
  // ---- GEMM0: Y = X(f32) @ W0, split-bf16 A (3 MFMA) ----
  int w    = threadIdx.x >> 6;
  int lane = threadIdx.x & 63;
  int m    = lane & 15;
  int kg   = lane >> 4;
  int row0 = ((int)blockIdx.x - cntB)*64 + w*16;

  f32x4 acc[8];
  #pragma unroll
  for (int t = 0; t < 8; ++t) acc[t] = (f32x4){0.f, 0.f, 0.f, 0.f};

  int arow = row0 + m;
  if (arow >= nrows) arow = nrows - 1;
  const float* ap0 = X + (size_t)arow*128 + (kg << 3);
  const short8* bh0 = (const short8*)Bh + lane;
  const short8* bl0 = (const short8*)Bl + lane;

  #pragma unroll
  for (int s = 0; s < 4; ++s){
    const float* ap = ap0 + s*32;
    float4 a0 = *(const float4*)ap;
    float4 a1 = *(const float4*)(ap + 4);
    float av[8] = {a0.x, a0.y, a0.z, a0.w, a1.x, a1.y, a1.z, a1.w};
    short8 ah, al;
    #pragma unroll
    for (int j = 0; j < 8; ++j){
      unsigned short hb = f32_to_bf16(av[j]);
      float hf = bf16lo_to_f32(hb);
      ah[j] = (short)hb;
      al[j] = (short)f32_to_bf16(av[j] - hf);
    }
    #pragma unroll
    for (int t = 0; t < 8; ++t){
      short8 bh = bh0[t*256 + s*64];
      short8 bl = bl0[t*256 + s*64];
      acc[t] = __builtin_amdgcn_mfma_f32_16x16x32_bf16(ah, bh, acc[t], 0, 0, 0);
      acc[t] = __builtin_amdgcn_mfma_f32_16x16x32_bf16(al, bh, acc[t], 0, 0, 0);
      acc[t] = __builtin_amdgcn_mfma_f32_16x16x32_bf16(ah, bl, acc[t], 0, 0, 0);
    }
  }
  #pragma unroll
  for (int t = 0; t < 8; ++t){
    #pragma unroll
    for (int r = 0; r < 4; ++r){
      int grow = row0 + (kg << 2) + r;
      if (grow < nrows) Y[(size_t)grow*128 + t*16 + m] = f32_to_bf16(acc[t][r]);
    }
  }
}

// ---- scan: block sums, then rowptr + dinv/selfn --------------------------

__global__ void k_scan_a(const unsigned int* __restrict__ cnt,
                         int* __restrict__ bsum, int n){
  int idx = blockIdx.x*256 + threadIdx.x;
  int v = (idx < n) ? (int)(cnt[idx] >> 24) : 0;
  #pragma unroll
  for (int o = 32; o >= 1; o >>= 1) v += __shfl_xor(v, o, 64);
  __shared__ int w4[4];
  if ((threadIdx.x & 63) == 0) w4[threadIdx.x >> 6] = v;
  __syncthreads();
  if (threadIdx.x == 0) bsum[blockIdx.x] = w4[0]+w4[1]+w4[2]+w4[3];
}

__global__ void k_scan_c(const unsigned int* __restrict__ cnt,
                         const int* __restrict__ bsum, int* __restrict__ rowptr,
                         float* __restrict__ dinv, float* __restrict__ selfn,
                         int n, int Etot, int nb){
  int tid = threadIdx.x;
  int bid = blockIdx.x;
  int lim = bid < nb ? bid : nb;
  int bv = (tid < lim) ? bsum[tid] : 0;
  #pragma unroll
  for (int o = 32; o >= 1; o >>= 1) bv += __shfl_xor(bv, o, 64);
  __shared__ int w4[4];
  __shared__ int s_boff;
  if ((tid & 63) == 0) w4[tid >> 6] = bv;
  __syncthreads();
  if (tid == 0) s_boff = w4[0]+w4[1]+w4[2]+w4[3];
  __syncthreads();

  int idx = bid*256 + tid;
  unsigned int c = (idx < n) ? cnt[idx] : 0u;
  int v = (int)(c >> 24);
  int ex = blk_excl_scan(v) + s_boff;
  if (idx < n){
    rowptr[idx] = ex;
    float wsum = (float)(c & 0xFFFFFFu) * (1.0f/262144.0f);
    float dg = 1.0f + wsum;               // + self-loop; always > 0
    dinv[idx]  = rsqrtf(dg);
    selfn[idx] = 1.0f / dg;
  }
  if (idx == 0) rowptr[n] = Etot;
}

// atomic-free fill with fused norm: csr = {src, dinv[s]*w*dinv[d]}
__global__ void k_fill(const int* __restrict__ src, const int* __restrict__ dst,
                       const float* __restrict__ w, const int* __restrict__ rowptr,
                       const int* __restrict__ pwr, const float* __restrict__ dinv,
                       int2* __restrict__ csr, int E){
  int e = blockIdx.x*blockDim.x + threadIdx.x;
  if (e >= E) return;
  int s = src[e], d = dst[e];
  float nr = dinv[s] * w[e] * dinv[d];
  csr[rowptr[d] + pwr[e]] = make_int2(s, __float_as_int(nr));
}

// ---- dense GEMM: Y[n,128](bf16) = Xb[n,128](bf16) @ W (B hi/lo split) ----

__global__ __launch_bounds__(256) void k_gemm_bf16(const unsigned short* __restrict__ Xb,
                                                   const short* __restrict__ Bh,
                                                   const short* __restrict__ Bl,
                                                   unsigned short* __restrict__ Y,
                                                   int nrows){
  int w    = threadIdx.x >> 6;
  int lane = threadIdx.x & 63;
  int m    = lane & 15;
  int kg   = lane >> 4;
  int row0 = blockIdx.x*64 + w*16;

  f32x4 acc[8];
  #pragma unroll
  for (int t = 0; t < 8; ++t) acc[t] = (f32x4){0.f, 0.f, 0.f, 0.f};

  int arow = row0 + m;
  if (arow >= nrows) arow = nrows - 1;
  const short8* ap = (const short8*)(Xb + (size_t)arow*128) + kg;
  const short8* bh0 = (const short8*)Bh + lane;
  const short8* bl0 = (const short8*)Bl + lane;

  #pragma unroll
  for (int s = 0; s < 4; ++s){
    short8 a = ap[s*4];
    #pragma unroll
    for (int t = 0; t < 8; ++t){
      acc[t] = __builtin_amdgcn_mfma_f32_16x16x32_bf16(a, bh0[t*256 + s*64], acc[t], 0, 0, 0);
      acc[t] = __builtin_amdgcn_mfma_f32_16x16x32_bf16(a, bl0[t*256 + s*64], acc[t], 0, 0, 0);
    }
  }
  #pragma unroll
  for (int t = 0; t < 8; ++t){
    #pragma unroll
    for (int r = 0; r < 4; ++r){
      int grow = row0 + (kg << 2) + r;
      if (grow < nrows) Y[(size_t)grow*128 + t*16 + m] = f32_to_bf16(acc[t][r]);
    }
  }
}

// ---- CSR gather + bias (+BN+leaky); Y bf16; out bf16 ---------------------
// one wave per node; 4 slots of 16 lanes; each slot owns 4 consecutive
// edges per 16-edge stride -> 16 row loads + 16 csr loads in flight

#define ACC4(v, nn) \
  acc[0] += (f32x2){bf16lo_to_f32((v).x), bf16hi_to_f32((v).x)} * (nn); \
  acc[1] += (f32x2){bf16lo_to_f32((v).y), bf16hi_to_f32((v).y)} * (nn); \
  acc[2] += (f32x2){bf16lo_to_f32((v).z), bf16hi_to_f32((v).z)} * (nn); \
  acc[3] += (f32x2){bf16lo_to_f32((v).w), bf16hi_to_f32((v).w)} * (nn);

template<bool BN>
__global__ __launch_bounds__(256) void k_gather(
    const unsigned short* __restrict__ Y, const int* __restrict__ rowptr,
    const int2* __restrict__ csr, const float* __restrict__ selfn,
    const float* __restrict__ bias,
    const float* __restrict__ gam, const float* __restrict__ bet,
    const float* __restrict__ mean, const float* __restrict__ var,
    unsigned int* __restrict__ outv, int n){
  int wid  = (blockIdx.x * blockDim.x + threadIdx.x) >> 6;   // node
  int lane = threadIdx.x & 63;
  if (wid >= n) return;
  int g = lane >> 4;          // edge slot 0..3
  int q = lane & 15;          // channel quad (8 channels)

  f32x2 acc[4];
  #pragma unroll
  for (int j = 0; j < 4; ++j) acc[j] = (f32x2){0.f, 0.f};

  int e0 = rowptr[wid], e1 = rowptr[wid+1];
  const char* Yb = (const char*)Y;

  int e = e0 + g*4;
  for (; e + 3 < e1; e += 16){
    int2 c0 = csr[e];
    int2 c1 = csr[e+1];
    int2 c2 = csr[e+2];
    int2 c3 = csr[e+3];
    uint4 v0 = *(const uint4*)(Yb + ((size_t)(unsigned)c0.x << 8) + (q << 4));
    uint4 v1 = *(const uint4*)(Yb + ((size_t)(unsigned)c1.x << 8) + (q << 4));
    uint4 v2 = *(const uint4*)(Yb + ((size_t)(unsigned)c2.x << 8) + (q << 4));
    uint4 v3 = *(const uint4*)(Yb + ((size_t)(unsigned)c3.x << 8) + (q << 4));
    float n0 = __int_as_float(c0.y), n1 = __int_as_float(c1.y);
    float n2 = __int_as_float(c2.y), n3 = __int_as_float(c3.y);
    ACC4(v0, n0); ACC4(v1, n1); ACC4(v2, n2); ACC4(v3, n3);
  }
  for (; e < e1; ++e){               // per-slot tail (never crosses +4)
    int2 c0 = csr[e];
    uint4 v0 = *(const uint4*)(Yb + ((size_t)(unsigned)c0.x << 8) + (q << 4));
    float n0 = __int_as_float(c0.y);
    ACC4(v0, n0);
  }

  float s[8] = {acc[0].x, acc[0].y, acc[1].x, acc[1].y,
                acc[2].x, acc[2].y, acc[3].x, acc[3].y};
  #pragma unroll
  for (int j = 0; j < 8; ++j){
    s[j] += __shfl_xor(s[j], 16, 64);
    s[j] += __shfl_xor(s[j], 32, 64);
  }

  if (g == 0){
    // self term
    uint4 v = *(const uint4*)(Yb + ((size_t)wid << 8) + (q << 4));
    float sf = selfn[wid];
    s[0] += bf16lo_to_f32(v.x)*sf; s[1] += bf16hi_to_f32(v.x)*sf;
    s[2] += bf16lo_to_f32(v.y)*sf; s[3] += bf16hi_to_f32(v.y)*sf;
    s[4] += bf16lo_to_f32(v.z)*sf; s[5] += bf16hi_to_f32(v.z)*sf;
    s[6] += bf16lo_to_f32(v.w)*sf; s[7] += bf16hi_to_f32(v.w)*sf;

    int c = q << 3;
    float4 bi0 = *(const float4*)&bias[c];
    float4 bi1 = *(const float4*)&bias[c+4];
    float o[8] = {s[0]+bi0.x, s[1]+bi0.y, s[2]+bi0.z, s[3]+bi0.w,
                  s[4]+bi1.x, s[5]+bi1.y, s[6]+bi1.z, s[7]+bi1.w};
    if (BN){
      float4 ga0 = *(const float4*)&gam[c],  ga1 = *(const float4*)&gam[c+4];
      float4 bt0 = *(const float4*)&bet[c],  bt1 = *(const float4*)&bet[c+4];
      float4 mn0 = *(const float4*)&mean[c], mn1 = *(const float4*)&mean[c+4];
      float4 vr0 = *(const float4*)&var[c],  vr1 = *(const float4*)&var[c+4];
      float gv[8] = {ga0.x,ga0.y,ga0.z,ga0.w, ga1.x,ga1.y,ga1.z,ga1.w};
      float bv[8] = {bt0.x,bt0.y,bt0.z,bt0.w, bt1.x,bt1.y,bt1.z,bt1.w};
      float mv[8] = {mn0.x,mn0.y,mn0.z,mn0.w, mn1.x,mn1.y,mn1.z,mn1.w};
      float vv[8] = {vr0.x,vr0.y,vr0.z,vr0.w, vr1.x,vr1.y,vr1.z,vr1.w};
      #pragma unroll
      for (int j = 0; j < 8; ++j){
        float a = gv[j] * rsqrtf(vv[j] + EPS);
        float t = (o[j] - mv[j]) * a + bv[j];
        o[j] = t > 0.f ? t : SLOPE*t;
      }
    }
    unsigned int p0 = ((unsigned int)f32_to_bf16(o[1]) << 16) | f32_to_bf16(o[0]);
    unsigned int p1 = ((unsigned int)f32_to_bf16(o[3]) << 16) | f32_to_bf16(o[2]);
    unsigned int p2 = ((unsigned int)f32_to_bf16(o[5]) << 16) | f32_to_bf16(o[4]);
    unsigned int p3 = ((unsigned int)f32_to_bf16(o[7]) << 16) | f32_to_bf16(o[6]);
    *(uint4*)((char*)outv + ((size_t)wid << 8) + (q << 4)) = make_uint4(p0,p1,p2,p3);
  }
}

// ---- mean pool over sorted batch (bf16 input, binary search) -------------

__global__ void k_pool(const unsigned int* __restrict__ h, const int* __restrict__ batch,
                       float* __restrict__ out, int n){
  __shared__ float2 red[1024];
  __shared__ int ss[2];
  int g = blockIdx.x;
  if (threadIdx.x < 2){
    int target = g + (int)threadIdx.x;
    int lo = 0, hi = n;
    while (lo < hi){ int mid = (lo + hi) >> 1; if (batch[mid] < target) lo = mid + 1; else hi = mid; }
    ss[threadIdx.x] = lo;
  }
  __syncthreads();
  int a = ss[0], b = ss[1];
  int rg = threadIdx.x >> 6;     // 0..15
  int c2 = threadIdx.x & 63;     // u32 pair index
  float sx = 0.f, sy = 0.f;
  for (int i = a + rg; i < b; i += 16){
    unsigned int v = h[((size_t)i << 6) + c2];
    sx += bf16lo_to_f32(v);
    sy += bf16hi_to_f32(v);
  }
  red[threadIdx.x] = make_float2(sx, sy);
  __syncthreads();
  if (rg == 0){
    float tx = 0.f, ty = 0.f;
    #pragma unroll
    for (int k = 0; k < 16; ++k){
      float2 r = red[c2 + k*64];
      tx += r.x; ty += r.y;
    }
    int cn = b - a;
    float inv = 1.0f / (float)(cn > 0 ? cn : 1);
    out[g*128 + 2*c2]     = tx * inv;
    out[g*128 + 2*c2 + 1] = ty * inv;
  }
}

// ---- launch --------------------------------------------------------------

extern "C" void kernel_launch(void* const* d_in, const int* in_sizes, int n_in,
                              void* d_out, int out_size, void* d_ws, size_t ws_size,
                              hipStream_t stream) {
  const int N = in_sizes[0] / 128;
  const int E = in_sizes[1];
  const int G = out_size / 128;
  const int NB = (N + 255) / 256;        // scan blocks
  const int CB = (E + 255) / 256;        // edge blocks
  const int GB = (N + 63) / 64;          // gemm blocks

  const float* x   = (const float*)d_in[0];
  const float* ew  = (const float*)d_in[1];
  const float* W0  = (const float*)d_in[2];
  const float* b0  = (const float*)d_in[3];
  const float* W1  = (const float*)d_in[4];
  const float* b1  = (const float*)d_in[5];
  const float* W2  = (const float*)d_in[6];
  const float* b2  = (const float*)d_in[7];
  const float* g0  = (const float*)d_in[8];
  const float* be0 = (const float*)d_in[9];
  const float* m0  = (const float*)d_in[10];
  const float* v0  = (const float*)d_in[11];
  const float* g1  = (const float*)d_in[12];
  const float* be1 = (const float*)d_in[13];
  const float* m1  = (const float*)d_in[14];
  const float* v1  = (const float*)d_in[15];
  const int*   ei  = (const int*)d_in[16];
  const int*   bat = (const int*)d_in[17];
  float* out = (float*)d_out;

  char* p = (char*)d_ws;
  auto alloc = [&](size_t bytes)->char*{
    char* q = p; p += (bytes + 255) & ~(size_t)255; return q;
  };
  unsigned int* cnt = (unsigned int*)alloc((size_t)N*4);
  float* dinv   = (float*)alloc((size_t)N*4);
  float* selfn  = (float*)alloc((size_t)N*4);
  int*   rowptr = (int*)  alloc((size_t)(N+1)*4);
  int*   pwr    = (int*)  alloc((size_t)E*4);
  int*   bsum   = (int*)  alloc((size_t)NB*4);
  int2*  csr    = (int2*) alloc((size_t)E*8);
  unsigned short* Y  = (unsigned short*)alloc((size_t)N*128*2);
  unsigned short* Hb = (unsigned short*)alloc((size_t)N*128*2);
  short* Bh = (short*)alloc(3*16384*2);
  short* Bl = (short*)alloc(3*16384*2);

  hipMemsetAsync(cnt, 0, (size_t)N*4, stream);

  const int* src = ei;
  const int* dst = ei + E;

  k_packW3<<<192, 256, 0, stream>>>(W0, W1, W2, Bh, Bl);
  k_fused0<<<CB + GB, 256, 0, stream>>>(dst, ew, cnt, pwr, E, CB, x, Bh, Bl, Y, N);
  k_scan_a<<<NB, 256, 0, stream>>>(cnt, bsum, N);
  k_scan_c<<<NB, 256, 0, stream>>>(cnt, bsum, rowptr, dinv, selfn, N, E, NB);
  k_fill  <<<CB, 256, 0, stream>>>(src, dst, ew, rowptr, pwr, dinv, csr, E);

  k_gather<true><<<(N+3)/4, 256, 0, stream>>>(Y, rowptr, csr, selfn,
                                              b0, g0, be0, m0, v0, (unsigned int*)Hb, N);
  k_gemm_bf16<<<GB, 256, 0, stream>>>(Hb, Bh + 16384, Bl + 16384, Y, N);
  k_gather<true><<<(N+3)/4, 256, 0, stream>>>(Y, rowptr, csr, selfn,
                                              b1, g1, be1, m1, v1, (unsigned int*)Hb, N);
  k_gemm_bf16<<<GB, 256, 0, stream>>>(Hb, Bh + 32768, Bl + 32768, Y, N);
  k_gather<false><<<(N+3)/4, 256, 0, stream>>>(Y, rowptr, csr, selfn,
                                               b2, nullptr, nullptr, nullptr, nullptr,
                                               (unsigned int*)Hb, N);
  k_pool<<<G, 1024, 0, stream>>>((const unsigned int*)Hb, bat, out, N);
}